// Round 4
// baseline (730.406 us; speedup 1.0000x reference)
//
#include <hip/hip_runtime.h>
#include <cstddef>

// Problem constants (from reference)
#define N0 200000
#define N1 50000
#define N2 10000
#define E0 800000
#define E1 160000
// feature dims: IN=H1=H2=256, EMB=128. K is always 256.

typedef short bf16x8 __attribute__((ext_vector_type(8)));            // 8 bf16 = 4 VGPRs
typedef float f32x4 __attribute__((ext_vector_type(4)));
typedef unsigned short us4 __attribute__((ext_vector_type(4)));      // 4 bf16 = 8 B

__device__ __forceinline__ unsigned short f2bf(float f) {
    unsigned int u = __float_as_uint(f);
    unsigned int r = (u + 0x7FFF + ((u >> 16) & 1)) >> 16;   // RNE
    return (unsigned short)r;
}
__device__ __forceinline__ float bf2f(unsigned short s) {
    return __uint_as_float(((unsigned int)s) << 16);
}

// ---------------- fused weight pre-pack: W [K][N] fp32 -> MFMA B-fragment bf16 ----------------
// tile = (ct,s): lane holds B[k = s*32 + (lane>>4)*8 + j][n = ct*16 + (lane&15)], j=0..7
// Bp index: ((ct*8 + s)*64 + lane)*8
__global__ void pack_all(const float* __restrict__ W1, const float* __restrict__ W2,
                         const float* __restrict__ Wp,
                         unsigned short* __restrict__ W1p, unsigned short* __restrict__ W2p,
                         unsigned short* __restrict__ Wpp) {
    int tid = blockIdx.x * 256 + threadIdx.x;
    if (tid >= 320 * 64) return;           // 128 + 128 + 64 tiles
    int lane = tid & 63;
    int tile = tid >> 6;
    const float* W; unsigned short* Bp; int N; int lt;
    if (tile < 128)      { W = W1; Bp = W1p; N = 256; lt = tile; }
    else if (tile < 256) { W = W2; Bp = W2p; N = 256; lt = tile - 128; }
    else                 { W = Wp; Bp = Wpp; N = 128; lt = tile - 256; }
    int s  = lt & 7;
    int ct = lt >> 3;
    int col = ct * 16 + (lane & 15);
    int k0  = s * 32 + (lane >> 4) * 8;
    unsigned short* dst = Bp + ((size_t)lt * 64 + lane) * 8;
#pragma unroll
    for (int j = 0; j < 8; j++) dst[j] = f2bf(W[(size_t)(k0 + j) * N + col]);
}

// ---------------- fused degree count + per-edge rank (both layers) ----------------
__global__ void count_all(const int* __restrict__ src0, const int* __restrict__ dst0,
                          const int* __restrict__ src1, const int* __restrict__ dst1,
                          int* __restrict__ cnt_out0, int* __restrict__ cnt_in0,
                          int* __restrict__ cnt_out1, int* __restrict__ cnt_in1,
                          int* __restrict__ rank0, int* __restrict__ rank1) {
    int e = blockIdx.x * 256 + threadIdx.x;
    if (e < E0) {
        atomicAdd(&cnt_out0[src0[e]], 1);
        rank0[e] = atomicAdd(&cnt_in0[dst0[e]], 1);
    } else if (e < E0 + E1) {
        int f = e - E0;
        atomicAdd(&cnt_out1[src1[f]], 1);
        rank1[f] = atomicAdd(&cnt_in1[dst1[f]], 1);
    }
}

// ---------------- counts -> rsqrt(max(cnt,1)) scales ----------------
__global__ void scales_kernel(const int* __restrict__ cnt, float* __restrict__ rs, int n) {
    int i = blockIdx.x * 256 + threadIdx.x;
    if (i < n) rs[i] = rsqrtf((float)max(cnt[i], 1));
}

// ---------------- 2-block exclusive scan: block 0 -> rowptr0, block 1 -> rowptr1 ----------------
__global__ __launch_bounds__(1024) void scan2(const int* __restrict__ cnt_in0, int* __restrict__ rowptr0,
                                              const int* __restrict__ cnt_in1, int* __restrict__ rowptr1) {
    const int* cnt = blockIdx.x ? cnt_in1 : cnt_in0;
    int* rowptr    = blockIdx.x ? rowptr1 : rowptr0;
    const int n    = blockIdx.x ? N2 : N1;
    __shared__ int partial[1024];
    const int t = threadIdx.x;
    const int chunk = (n + 1023) / 1024;
    const int begin = t * chunk;
    const int end = min(begin + chunk, n);
    int sum = 0;
    for (int i = begin; i < end; i++) sum += cnt[i];
    partial[t] = sum;
    __syncthreads();
    for (int off = 1; off < 1024; off <<= 1) {
        int v = (t >= off) ? partial[t - off] : 0;
        __syncthreads();
        partial[t] += v;
        __syncthreads();
    }
    int run = partial[t] - sum;
    for (int i = begin; i < end; i++) {
        rowptr[i] = run;
        run += cnt[i];
    }
    if (t == 1023) rowptr[n] = partial[1023];
}

// ---------------- fused CSR fill (both layers) ----------------
__global__ void fill_all(const int* __restrict__ src0, const int* __restrict__ dst0,
                         const int* __restrict__ src1, const int* __restrict__ dst1,
                         const int* __restrict__ rank0, const int* __restrict__ rank1,
                         const int* __restrict__ rowptr0, const int* __restrict__ rowptr1,
                         int* __restrict__ csr0, int* __restrict__ csr1) {
    int e = blockIdx.x * 256 + threadIdx.x;
    if (e < E0) {
        csr0[rowptr0[dst0[e]] + rank0[e]] = src0[e];
    } else if (e < E0 + E1) {
        int f = e - E0;
        csr1[rowptr1[dst1[f]] + rank1[f]] = src1[f];
    }
}

// ---------------- bf16 MFMA GEMM: C[M,N] = A[M,256] @ Bp (+epilogue) ----------------
// block = 256 thr = 4 waves; BM=64; wave w owns NCT 16-col tiles. No LDS.
// AF32: A is fp32 (converted in-register), else A is bf16 row-major.
// rs (nullable): per-ROW scale applied after matmul. bias (nullable): per-col add.
// OBF16: store bf16, else fp32.
template <int NCT, bool AF32, bool OBF16>
__global__ __launch_bounds__(256) void gemm_mfma(const void* __restrict__ A_,
                                                 const unsigned short* __restrict__ Bp,
                                                 const float* __restrict__ rs,
                                                 const float* __restrict__ bias,
                                                 void* __restrict__ C_, int M, int N) {
    const int lane = threadIdx.x & 63;
    const int wave = threadIdx.x >> 6;            // 0..3
    const int rowBase = blockIdx.x * 64;
    const int colBase = wave * (NCT * 16);
    const int lm = lane & 15;
    const int quad = lane >> 4;                   // 0..3

    f32x4 acc[4][NCT];
#pragma unroll
    for (int rt = 0; rt < 4; rt++)
#pragma unroll
        for (int ct = 0; ct < NCT; ct++) acc[rt][ct] = (f32x4){0.f, 0.f, 0.f, 0.f};

    int rowIdx[4];
#pragma unroll
    for (int rt = 0; rt < 4; rt++) rowIdx[rt] = min(rowBase + rt * 16 + lm, M - 1);

    const float* af32 = (const float*)A_;
    const unsigned short* abf = (const unsigned short*)A_;

#pragma unroll
    for (int s = 0; s < 8; s++) {                 // K = 256, 32 per step
        bf16x8 afrag[4];
#pragma unroll
        for (int rt = 0; rt < 4; rt++) {
            if (AF32) {
                const float* p = af32 + (size_t)rowIdx[rt] * 256 + quad * 8 + s * 32;
                float4 x = *(const float4*)p;
                float4 y = *(const float4*)(p + 4);
                union { unsigned short u[8]; bf16x8 v; } af;
                af.u[0] = f2bf(x.x); af.u[1] = f2bf(x.y); af.u[2] = f2bf(x.z); af.u[3] = f2bf(x.w);
                af.u[4] = f2bf(y.x); af.u[5] = f2bf(y.y); af.u[6] = f2bf(y.z); af.u[7] = f2bf(y.w);
                afrag[rt] = af.v;
            } else {
                afrag[rt] = *(const bf16x8*)(abf + (size_t)rowIdx[rt] * 256 + quad * 8 + s * 32);
            }
        }
#pragma unroll
        for (int ct = 0; ct < NCT; ct++) {
            bf16x8 bfrag = *(const bf16x8*)(Bp + (((size_t)(wave * NCT + ct) * 8 + s) * 64 + lane) * 8);
#pragma unroll
            for (int rt = 0; rt < 4; rt++)
                acc[rt][ct] = __builtin_amdgcn_mfma_f32_16x16x32_bf16(afrag[rt], bfrag, acc[rt][ct], 0, 0, 0);
        }
    }

    // epilogue: C layout col=lane&15, row=quad*4+i
#pragma unroll
    for (int rt = 0; rt < 4; rt++) {
        f32x4 rsv = (f32x4){1.f, 1.f, 1.f, 1.f};
        if (rs) rsv = *(const f32x4*)(rs + rowBase + rt * 16 + quad * 4);
#pragma unroll
        for (int ct = 0; ct < NCT; ct++) {
            int col = colBase + ct * 16 + lm;
            float bv = bias ? bias[col] : 0.0f;
#pragma unroll
            for (int i = 0; i < 4; i++) {
                int row = rowBase + rt * 16 + quad * 4 + i;
                if (row < M) {
                    float v = acc[rt][ct][i] * rsv[i] + bv;
                    if (OBF16) ((unsigned short*)C_)[(size_t)row * N + col] = f2bf(v);
                    else       ((float*)C_)[(size_t)row * N + col] = v;
                }
            }
        }
    }
}

// ---------------- gather over pre-scaled bf16 rows: out = bf16(sum * rs_dst + bias) ----------------
// one wave per dst row; lane covers cols lane*4..lane*4+3 (512 B rows).
__global__ __launch_bounds__(256) void gather_bf16(const unsigned short* __restrict__ Y,
                                                   const int* __restrict__ rowptr,
                                                   const int* __restrict__ csr,
                                                   const float* __restrict__ rs_dst,
                                                   const float* __restrict__ bias,
                                                   unsigned short* __restrict__ outb, int n_dst) {
    int w    = (blockIdx.x * 256 + threadIdx.x) >> 6;
    int lane = threadIdx.x & 63;
    if (w >= n_dst) return;
    int e   = rowptr[w];
    int end = rowptr[w + 1];
    f32x4 acc = (f32x4){0.f, 0.f, 0.f, 0.f};
    for (; e + 3 < end; e += 4) {
        int s0 = csr[e], s1 = csr[e + 1], s2 = csr[e + 2], s3 = csr[e + 3];
        us4 v0 = *(const us4*)(Y + (size_t)s0 * 256 + lane * 4);
        us4 v1 = *(const us4*)(Y + (size_t)s1 * 256 + lane * 4);
        us4 v2 = *(const us4*)(Y + (size_t)s2 * 256 + lane * 4);
        us4 v3 = *(const us4*)(Y + (size_t)s3 * 256 + lane * 4);
        acc[0] += bf2f(v0[0]) + bf2f(v1[0]) + bf2f(v2[0]) + bf2f(v3[0]);
        acc[1] += bf2f(v0[1]) + bf2f(v1[1]) + bf2f(v2[1]) + bf2f(v3[1]);
        acc[2] += bf2f(v0[2]) + bf2f(v1[2]) + bf2f(v2[2]) + bf2f(v3[2]);
        acc[3] += bf2f(v0[3]) + bf2f(v1[3]) + bf2f(v2[3]) + bf2f(v3[3]);
    }
    for (; e < end; e++) {
        int s0 = csr[e];
        us4 v0 = *(const us4*)(Y + (size_t)s0 * 256 + lane * 4);
        acc[0] += bf2f(v0[0]); acc[1] += bf2f(v0[1]); acc[2] += bf2f(v0[2]); acc[3] += bf2f(v0[3]);
    }
    float sd = rs_dst[w];
    f32x4 b = *(const f32x4*)(bias + lane * 4);
    us4 o;
    o[0] = f2bf(acc[0] * sd + b[0]);
    o[1] = f2bf(acc[1] * sd + b[1]);
    o[2] = f2bf(acc[2] * sd + b[2]);
    o[3] = f2bf(acc[3] * sd + b[3]);
    *(us4*)(outb + (size_t)w * 256 + lane * 4) = o;
}

extern "C" void kernel_launch(void* const* d_in, const int* in_sizes, int n_in,
                              void* d_out, int out_size, void* d_ws, size_t ws_size,
                              hipStream_t stream) {
    const float* h    = (const float*)d_in[0];
    const int*   src0 = (const int*)d_in[1];
    const int*   dst0 = (const int*)d_in[2];
    const int*   src1 = (const int*)d_in[3];
    const int*   dst1 = (const int*)d_in[4];
    const float* W1   = (const float*)d_in[5];
    const float* b1   = (const float*)d_in[6];
    const float* W2   = (const float*)d_in[7];
    const float* b2   = (const float*)d_in[8];
    const float* Wp   = (const float*)d_in[9];
    const float* bp   = (const float*)d_in[10];
    float* out = (float*)d_out;

    // ---------------- workspace layout (with liveness-based aliasing) ----------------
    int* ib = (int*)d_ws;
    int* cnt_out0 = ib;                      // N0            [live: count..scales]
    int* cnt_in0  = cnt_out0 + N0;           // N1
    int* cnt_out1 = cnt_in0 + N1;            // N1
    int* cnt_in1  = cnt_out1 + N1;           // N2   (counts contiguous: 310000)
    int* rowptr0  = ib + 310000;             // N1+1          [live: scan..gather0]
    int* rowptr1  = ib + 360001;             // N2+1
    int* csr0     = ib + 370004;             // E0            [live: fill..gather0]
    int* csr1     = ib + 1170004;            // E1            -> ints end at 1,330,004
    float* fb = (float*)(ib + 1330004);
    float* rs_out0 = fb;                     // N0   (same order as counts)
    float* rs_in0  = fb + 200000;            // N1
    float* rs_out1 = fb + 250000;            // N1
    float* rs_in1  = fb + 300000;            // N2   (scales contiguous: 310000)
    unsigned short* wpk = (unsigned short*)(fb + 310000);
    unsigned short* W1p = wpk;               // 256*256
    unsigned short* W2p = wpk + 65536;       // 256*256
    unsigned short* Wpp = wpk + 131072;      // 256*128  -> 163840 ushorts
    // big aliased region R (102.4 MB): rank (dead before gemm1) / Y1 (dead after gather0)
    //                                  / {Y2, h2} (born at gemm2)
    unsigned short* R   = wpk + 163840;
    int* rank0 = (int*)R;                    // E0   [live: count..fill]
    int* rank1 = rank0 + E0;                 // E1
    unsigned short* Y1  = R;                 // N0*256 bf16   [live: gemm1..gather0]
    unsigned short* Y2  = R;                 // N1*256 bf16   [live: gemm2..gather1]
    unsigned short* h2b = R + (size_t)N1 * 256;  // N2*256 bf16 [live: gather1..gemmp]
    unsigned short* h1b = R + (size_t)N0 * 256;  // N1*256 bf16 [live: gather0..gemm2]

    // 1. zero count region (1.24 MB)
    hipMemsetAsync(cnt_out0, 0, (size_t)310000 * sizeof(int), stream);

    // 2. pack all three weight matrices into MFMA B-fragment layout
    pack_all<<<80, 256, 0, stream>>>(W1, W2, Wp, W1p, W2p, Wpp);

    // 3. degree counts + ranks (both layers, one dispatch)
    count_all<<<(E0 + E1 + 255) / 256, 256, 0, stream>>>(src0, dst0, src1, dst1,
                                                         cnt_out0, cnt_in0, cnt_out1, cnt_in1,
                                                         rank0, rank1);

    // 4. scales = rsqrt(max(cnt,1)) for all 4 arrays
    scales_kernel<<<(310000 + 255) / 256, 256, 0, stream>>>(cnt_out0, rs_out0, 310000);

    // 5. rowptrs (both layers, one dispatch)
    scan2<<<2, 1024, 0, stream>>>(cnt_in0, rowptr0, cnt_in1, rowptr1);

    // 6. CSR fill (both layers, one dispatch)
    fill_all<<<(E0 + E1 + 255) / 256, 256, 0, stream>>>(src0, dst0, src1, dst1,
                                                        rank0, rank1, rowptr0, rowptr1, csr0, csr1);

    // 7. Y1 = (h @ W1) * rs_out0[row]   [200000 x 256] bf16, pre-scaled
    gemm_mfma<4, true, true><<<N0 / 64, 256, 0, stream>>>(h, W1p, rs_out0, nullptr, Y1, N0, 256);

    // 8. h1 = bf16( sum_{src} Y1[src] * rs_in0[dst] + b1 )   [50000 x 256]
    gather_bf16<<<(N1 + 3) / 4, 256, 0, stream>>>(Y1, rowptr0, csr0, rs_in0, b1, h1b, N1);

    // 9. Y2 = (h1 @ W2) * rs_out1[row]  [50000 x 256] bf16
    gemm_mfma<4, false, true><<<(N1 + 63) / 64, 256, 0, stream>>>(h1b, W2p, rs_out1, nullptr, Y2, N1, 256);

    // 10. h2 = bf16( sum Y2[src] * rs_in1[dst] + b2 )   [10000 x 256]
    gather_bf16<<<(N2 + 3) / 4, 256, 0, stream>>>(Y2, rowptr1, csr1, rs_in1, b2, h2b, N2);

    // 11. out = h2 @ Wp + bp   [10000 x 128] fp32
    gemm_mfma<2, false, false><<<(N2 + 63) / 64, 256, 0, stream>>>(h2b, Wpp, nullptr, bp, out, N2, 128);
}

// Round 5
// 709.200 us; speedup vs baseline: 1.0299x; 1.0299x over previous
//
#include <hip/hip_runtime.h>
#include <cstddef>

// Problem constants (from reference)
#define N0 200000
#define N1 50000
#define N2 10000
#define E0 800000
#define E1 160000
// feature dims: IN=H1=H2=256, EMB=128. K is always 256.

typedef short bf16x8 __attribute__((ext_vector_type(8)));            // 8 bf16 = 4 VGPRs
typedef float f32x4 __attribute__((ext_vector_type(4)));
typedef unsigned short us8 __attribute__((ext_vector_type(8)));      // 8 bf16 = 16 B

__device__ __forceinline__ unsigned short f2bf(float f) {
    unsigned int u = __float_as_uint(f);
    unsigned int r = (u + 0x7FFF + ((u >> 16) & 1)) >> 16;   // RNE
    return (unsigned short)r;
}
__device__ __forceinline__ float bf2f(unsigned short s) {
    return __uint_as_float(((unsigned int)s) << 16);
}

// ---------------- fused weight pre-pack: W [K][N] fp32 -> MFMA B-fragment bf16 ----------------
// tile = (ct,s): lane holds B[k = s*32 + (lane>>4)*8 + j][n = ct*16 + (lane&15)], j=0..7
// Bp index: ((ct*8 + s)*64 + lane)*8
__global__ void pack_all(const float* __restrict__ W1, const float* __restrict__ W2,
                         const float* __restrict__ Wp,
                         unsigned short* __restrict__ W1p, unsigned short* __restrict__ W2p,
                         unsigned short* __restrict__ Wpp) {
    int tid = blockIdx.x * 256 + threadIdx.x;
    if (tid >= 320 * 64) return;           // 128 + 128 + 64 tiles
    int lane = tid & 63;
    int tile = tid >> 6;
    const float* W; unsigned short* Bp; int N; int lt;
    if (tile < 128)      { W = W1; Bp = W1p; N = 256; lt = tile; }
    else if (tile < 256) { W = W2; Bp = W2p; N = 256; lt = tile - 128; }
    else                 { W = Wp; Bp = Wpp; N = 128; lt = tile - 256; }
    int s  = lt & 7;
    int ct = lt >> 3;
    int col = ct * 16 + (lane & 15);
    int k0  = s * 32 + (lane >> 4) * 8;
    unsigned short* dst = Bp + ((size_t)lt * 64 + lane) * 8;
#pragma unroll
    for (int j = 0; j < 8; j++) dst[j] = f2bf(W[(size_t)(k0 + j) * N + col]);
}

// ---------------- fused degree count + per-edge rank (both layers) ----------------
__global__ void count_all(const int* __restrict__ src0, const int* __restrict__ dst0,
                          const int* __restrict__ src1, const int* __restrict__ dst1,
                          int* __restrict__ cnt_out0, int* __restrict__ cnt_in0,
                          int* __restrict__ cnt_out1, int* __restrict__ cnt_in1,
                          int* __restrict__ rank0, int* __restrict__ rank1) {
    int e = blockIdx.x * 256 + threadIdx.x;
    if (e < E0) {
        atomicAdd(&cnt_out0[src0[e]], 1);
        rank0[e] = atomicAdd(&cnt_in0[dst0[e]], 1);
    } else if (e < E0 + E1) {
        int f = e - E0;
        atomicAdd(&cnt_out1[src1[f]], 1);
        rank1[f] = atomicAdd(&cnt_in1[dst1[f]], 1);
    }
}

// ---------------- counts -> rsqrt(max(cnt,1)) scales ----------------
__global__ void scales_kernel(const int* __restrict__ cnt, float* __restrict__ rs, int n) {
    int i = blockIdx.x * 256 + threadIdx.x;
    if (i < n) rs[i] = rsqrtf((float)max(cnt[i], 1));
}

// ---------------- 2-block exclusive scan: block 0 -> rowptr0, block 1 -> rowptr1 ----------------
__global__ __launch_bounds__(1024) void scan2(const int* __restrict__ cnt_in0, int* __restrict__ rowptr0,
                                              const int* __restrict__ cnt_in1, int* __restrict__ rowptr1) {
    const int* cnt = blockIdx.x ? cnt_in1 : cnt_in0;
    int* rowptr    = blockIdx.x ? rowptr1 : rowptr0;
    const int n    = blockIdx.x ? N2 : N1;
    __shared__ int partial[1024];
    const int t = threadIdx.x;
    const int chunk = (n + 1023) / 1024;
    const int begin = t * chunk;
    const int end = min(begin + chunk, n);
    int sum = 0;
    for (int i = begin; i < end; i++) sum += cnt[i];
    partial[t] = sum;
    __syncthreads();
    for (int off = 1; off < 1024; off <<= 1) {
        int v = (t >= off) ? partial[t - off] : 0;
        __syncthreads();
        partial[t] += v;
        __syncthreads();
    }
    int run = partial[t] - sum;
    for (int i = begin; i < end; i++) {
        rowptr[i] = run;
        run += cnt[i];
    }
    if (t == 1023) rowptr[n] = partial[1023];
}

// ---------------- fused CSR fill (both layers) ----------------
__global__ void fill_all(const int* __restrict__ src0, const int* __restrict__ dst0,
                         const int* __restrict__ src1, const int* __restrict__ dst1,
                         const int* __restrict__ rank0, const int* __restrict__ rank1,
                         const int* __restrict__ rowptr0, const int* __restrict__ rowptr1,
                         int* __restrict__ csr0, int* __restrict__ csr1) {
    int e = blockIdx.x * 256 + threadIdx.x;
    if (e < E0) {
        csr0[rowptr0[dst0[e]] + rank0[e]] = src0[e];
    } else if (e < E0 + E1) {
        int f = e - E0;
        csr1[rowptr1[dst1[f]] + rank1[f]] = src1[f];
    }
}

// ---------------- bf16 MFMA GEMM: wave = 16 rows x full N ----------------
// block = 256 thr = 4 waves = 64 distinct rows (A read once per block).
// NT = N/16 col-tiles, all owned by each wave (B is small + L2-resident).
// AF32: A fp32 (in-register convert), else bf16. rs: per-row scale. bias: per-col. OBF16: bf16 out.
template <int NT, bool AF32, bool OBF16>
__global__ __launch_bounds__(256) void gemm_mfma(const void* __restrict__ A_,
                                                 const unsigned short* __restrict__ Bp,
                                                 const float* __restrict__ rs,
                                                 const float* __restrict__ bias,
                                                 void* __restrict__ C_, int M, int N) {
    const int lane = threadIdx.x & 63;
    const int wave = threadIdx.x >> 6;            // 0..3
    const int rowBase = blockIdx.x * 64 + wave * 16;
    const int lm = lane & 15;
    const int quad = lane >> 4;                   // 0..3

    f32x4 acc[NT];
#pragma unroll
    for (int ct = 0; ct < NT; ct++) acc[ct] = (f32x4){0.f, 0.f, 0.f, 0.f};

    const int rowA = min(rowBase + lm, M - 1);
    const float* af32 = (const float*)A_ + (size_t)rowA * 256 + quad * 8;
    const unsigned short* abf = (const unsigned short*)A_ + (size_t)rowA * 256 + quad * 8;

#pragma unroll 2
    for (int s = 0; s < 8; s++) {                 // K = 256, 32 per step
        bf16x8 afrag;
        if (AF32) {
            float4 x = *(const float4*)(af32 + s * 32);
            float4 y = *(const float4*)(af32 + s * 32 + 4);
            union { unsigned short u[8]; bf16x8 v; } af;
            af.u[0] = f2bf(x.x); af.u[1] = f2bf(x.y); af.u[2] = f2bf(x.z); af.u[3] = f2bf(x.w);
            af.u[4] = f2bf(y.x); af.u[5] = f2bf(y.y); af.u[6] = f2bf(y.z); af.u[7] = f2bf(y.w);
            afrag = af.v;
        } else {
            afrag = *(const bf16x8*)(abf + s * 32);
        }
#pragma unroll
        for (int ct = 0; ct < NT; ct++) {
            bf16x8 bfrag = *(const bf16x8*)(Bp + (((size_t)ct * 8 + s) * 64 + lane) * 8);
            acc[ct] = __builtin_amdgcn_mfma_f32_16x16x32_bf16(afrag, bfrag, acc[ct], 0, 0, 0);
        }
    }

    // epilogue: C layout col=lane&15, row=quad*4+i
    f32x4 rsv = (f32x4){1.f, 1.f, 1.f, 1.f};
    if (rs) rsv = *(const f32x4*)(rs + rowBase + quad * 4);
#pragma unroll
    for (int ct = 0; ct < NT; ct++) {
        int col = ct * 16 + lm;
        float bv = bias ? bias[col] : 0.0f;
#pragma unroll
        for (int i = 0; i < 4; i++) {
            int row = rowBase + quad * 4 + i;
            if (row < M) {
                float v = acc[ct][i] * rsv[i] + bv;
                if (OBF16) ((unsigned short*)C_)[(size_t)row * N + col] = f2bf(v);
                else       ((float*)C_)[(size_t)row * N + col] = v;
            }
        }
    }
}

// ---------------- gather over pre-scaled bf16 rows (split-lane, 16 B/lane) ----------------
// one wave per dst row; lanes 0-31 and 32-63 process different edges of the same row.
// lane covers cols (lane&31)*8 .. +7; halves combined by shfl_xor(32) at the end.
__global__ __launch_bounds__(256) void gather_bf16(const unsigned short* __restrict__ Y,
                                                   const int* __restrict__ rowptr,
                                                   const int* __restrict__ csr,
                                                   const float* __restrict__ rs_dst,
                                                   const float* __restrict__ bias,
                                                   unsigned short* __restrict__ outb, int n_dst) {
    int w    = (blockIdx.x * 256 + threadIdx.x) >> 6;
    int lane = threadIdx.x & 63;
    if (w >= n_dst) return;
    int half = lane >> 5;
    int l32  = lane & 31;
    int e   = rowptr[w];
    int end = rowptr[w + 1];
    float acc[8] = {0.f, 0.f, 0.f, 0.f, 0.f, 0.f, 0.f, 0.f};
    // main: 8 edges per iteration (4 per half, 4 independent 16B loads in flight)
    for (; e + 7 < end; e += 8) {
        int s0 = csr[e + half];
        int s1 = csr[e + 2 + half];
        int s2 = csr[e + 4 + half];
        int s3 = csr[e + 6 + half];
        us8 v0 = *(const us8*)(Y + (size_t)s0 * 256 + l32 * 8);
        us8 v1 = *(const us8*)(Y + (size_t)s1 * 256 + l32 * 8);
        us8 v2 = *(const us8*)(Y + (size_t)s2 * 256 + l32 * 8);
        us8 v3 = *(const us8*)(Y + (size_t)s3 * 256 + l32 * 8);
#pragma unroll
        for (int j = 0; j < 8; j++)
            acc[j] += (bf2f(v0[j]) + bf2f(v1[j])) + (bf2f(v2[j]) + bf2f(v3[j]));
    }
    // pairs: 2 edges per iteration (both halves in-bounds)
    for (; e + 1 < end; e += 2) {
        int s0 = csr[e + half];
        us8 v0 = *(const us8*)(Y + (size_t)s0 * 256 + l32 * 8);
#pragma unroll
        for (int j = 0; j < 8; j++) acc[j] += bf2f(v0[j]);
    }
    // final odd edge: half 0 only
    if (e < end && half == 0) {
        int s0 = csr[e];
        us8 v0 = *(const us8*)(Y + (size_t)s0 * 256 + l32 * 8);
#pragma unroll
        for (int j = 0; j < 8; j++) acc[j] += bf2f(v0[j]);
    }
    // combine halves
#pragma unroll
    for (int j = 0; j < 8; j++) acc[j] += __shfl_xor(acc[j], 32);
    if (half == 0) {
        float sd = rs_dst[w];
        f32x4 ba = *(const f32x4*)(bias + l32 * 8);
        f32x4 bb = *(const f32x4*)(bias + l32 * 8 + 4);
        us8 o;
        o[0] = f2bf(acc[0] * sd + ba[0]);
        o[1] = f2bf(acc[1] * sd + ba[1]);
        o[2] = f2bf(acc[2] * sd + ba[2]);
        o[3] = f2bf(acc[3] * sd + ba[3]);
        o[4] = f2bf(acc[4] * sd + bb[0]);
        o[5] = f2bf(acc[5] * sd + bb[1]);
        o[6] = f2bf(acc[6] * sd + bb[2]);
        o[7] = f2bf(acc[7] * sd + bb[3]);
        *(us8*)(outb + (size_t)w * 256 + l32 * 8) = o;
    }
}

extern "C" void kernel_launch(void* const* d_in, const int* in_sizes, int n_in,
                              void* d_out, int out_size, void* d_ws, size_t ws_size,
                              hipStream_t stream) {
    const float* h    = (const float*)d_in[0];
    const int*   src0 = (const int*)d_in[1];
    const int*   dst0 = (const int*)d_in[2];
    const int*   src1 = (const int*)d_in[3];
    const int*   dst1 = (const int*)d_in[4];
    const float* W1   = (const float*)d_in[5];
    const float* b1   = (const float*)d_in[6];
    const float* W2   = (const float*)d_in[7];
    const float* b2   = (const float*)d_in[8];
    const float* Wp   = (const float*)d_in[9];
    const float* bp   = (const float*)d_in[10];
    float* out = (float*)d_out;

    // ---------------- workspace layout (with liveness-based aliasing) ----------------
    int* ib = (int*)d_ws;
    int* cnt_out0 = ib;                      // N0            [live: count..scales]
    int* cnt_in0  = cnt_out0 + N0;           // N1
    int* cnt_out1 = cnt_in0 + N1;            // N1
    int* cnt_in1  = cnt_out1 + N1;           // N2   (counts contiguous: 310000)
    int* rowptr0  = ib + 310000;             // N1+1          [live: scan..gather0]
    int* rowptr1  = ib + 360001;             // N2+1
    int* csr0     = ib + 370004;             // E0            [live: fill..gather0]
    int* csr1     = ib + 1170004;            // E1            -> ints end at 1,330,004
    float* fb = (float*)(ib + 1330004);
    float* rs_out0 = fb;                     // N0   (same order as counts)
    float* rs_in0  = fb + 200000;            // N1
    float* rs_out1 = fb + 250000;            // N1
    float* rs_in1  = fb + 300000;            // N2   (scales contiguous: 310000)
    unsigned short* wpk = (unsigned short*)(fb + 310000);
    unsigned short* W1p = wpk;               // 256*256
    unsigned short* W2p = wpk + 65536;       // 256*256
    unsigned short* Wpp = wpk + 131072;      // 256*128  -> 163840 ushorts
    // big aliased region R (102.4 MB): rank (dead before gemm1) / Y1 (dead after gather0)
    //                                  / {Y2, h2} (born at gemm2)
    unsigned short* R   = wpk + 163840;
    int* rank0 = (int*)R;                    // E0   [live: count..fill]
    int* rank1 = rank0 + E0;                 // E1
    unsigned short* Y1  = R;                 // N0*256 bf16   [live: gemm1..gather0]
    unsigned short* Y2  = R;                 // N1*256 bf16   [live: gemm2..gather1]
    unsigned short* h2b = R + (size_t)N1 * 256;  // N2*256 bf16 [live: gather1..gemmp]
    unsigned short* h1b = R + (size_t)N0 * 256;  // N1*256 bf16 [live: gather0..gemm2]

    // 1. zero count region (1.24 MB)
    hipMemsetAsync(cnt_out0, 0, (size_t)310000 * sizeof(int), stream);

    // 2. pack all three weight matrices into MFMA B-fragment layout
    pack_all<<<80, 256, 0, stream>>>(W1, W2, Wp, W1p, W2p, Wpp);

    // 3. degree counts + ranks (both layers, one dispatch)
    count_all<<<(E0 + E1 + 255) / 256, 256, 0, stream>>>(src0, dst0, src1, dst1,
                                                         cnt_out0, cnt_in0, cnt_out1, cnt_in1,
                                                         rank0, rank1);

    // 4. scales = rsqrt(max(cnt,1)) for all 4 arrays
    scales_kernel<<<(310000 + 255) / 256, 256, 0, stream>>>(cnt_out0, rs_out0, 310000);

    // 5. rowptrs (both layers, one dispatch)
    scan2<<<2, 1024, 0, stream>>>(cnt_in0, rowptr0, cnt_in1, rowptr1);

    // 6. CSR fill (both layers, one dispatch)
    fill_all<<<(E0 + E1 + 255) / 256, 256, 0, stream>>>(src0, dst0, src1, dst1,
                                                        rank0, rank1, rowptr0, rowptr1, csr0, csr1);

    // 7. Y1 = (h @ W1) * rs_out0[row]   [200000 x 256] bf16, pre-scaled
    gemm_mfma<16, true, true><<<N0 / 64, 256, 0, stream>>>(h, W1p, rs_out0, nullptr, Y1, N0, 256);

    // 8. h1 = bf16( sum_{src} Y1[src] * rs_in0[dst] + b1 )   [50000 x 256]
    gather_bf16<<<(N1 + 3) / 4, 256, 0, stream>>>(Y1, rowptr0, csr0, rs_in0, b1, h1b, N1);

    // 9. Y2 = (h1 @ W2) * rs_out1[row]  [50000 x 256] bf16
    gemm_mfma<16, false, true><<<(N1 + 63) / 64, 256, 0, stream>>>(h1b, W2p, rs_out1, nullptr, Y2, N1, 256);

    // 10. h2 = bf16( sum Y2[src] * rs_in1[dst] + b2 )   [10000 x 256]
    gather_bf16<<<(N2 + 3) / 4, 256, 0, stream>>>(Y2, rowptr1, csr1, rs_in1, b2, h2b, N2);

    // 11. out = h2 @ Wp + bp   [10000 x 128] fp32
    gemm_mfma<8, false, false><<<(N2 + 63) / 64, 256, 0, stream>>>(h2b, Wpp, nullptr, bp, out, N2, 128);
}